// Round 2
// baseline (8298.431 us; speedup 1.0000x reference)
//
#include <hip/hip_runtime.h>

// Problem constants: T=32 enc + 32 dec, B=64, N=64, H=128, Din=Dout=1
#define NB 64
#define NN 64
#define NH 128

// ---- LDS layout (floats) -------------------------------------------------
#define OFF_H0    0        // [64][128] state layer0
#define OFF_H1    8192     // [64][128] state layer1
#define OFF_MT    16384    // [128][64] Mt[feat][node] = (S@src)^T
#define OFF_RH    24576    // [64][128] r*h
#define OFF_WS    32768    // [2][8][384] W staging (double buffered)
#define OFF_XS    38912    // [64] sparse x
#define OFF_MP    38976    // [4][64] partials (Mxv / proj)
#define OFF_MXV   39232    // [64] S@x for sparse cells
#define OFF_WP    39296    // [128] Wp
#define OFF_W0RU  39424    // [256] Wru row 0 (sparse)
#define OFF_W0C   39680    // [128] Wc row 0 (sparse)
#define LDS_FLOATS 39808
#define LDS_BYTES  (LDS_FLOATS * 4)   // 159232 <= 160 KiB

struct KParams {
  const float* inp;   // [32,64,64]
  const float* S;     // [64,64,64]
  const float* w[16]; // e0{Wru,bru,Wc,bc} e1{..} d0{..} db{..}
  const float* Wp;    // [128]
  const float* bp;    // [1]
  float* out;         // [32,64,64]
  float* stg;         // ws: S transposed per batch [64][64][64] (St[b][m][r]=S[b][r][m])
};

__device__ __forceinline__ float sigm(float v) { return 1.f / (1.f + __expf(-v)); }

// Mt[f][r] = sum_m src[m][f] * St[m][r]   (i.e. (S@src) stored transposed)
// src: LDS [64][128]; stb: global St for this batch [64][64]
__device__ __forceinline__ void mixt(float* __restrict__ Mt, const float* __restrict__ src,
                                     const float* __restrict__ stb, int tid)
{
  const int ntx = tid & 15, nty = tid >> 4;     // node0 = 4*ntx, feat0 = 8*nty
  const int n0 = 4 * ntx, f0 = 8 * nty;
  float acc[8][4];
  #pragma unroll
  for (int i = 0; i < 8; ++i)
    #pragma unroll
    for (int j = 0; j < 4; ++j) acc[i][j] = 0.f;
  #pragma unroll 4
  for (int m = 0; m < 64; ++m) {
    const float4 a0 = *(const float4*)&src[m * 128 + f0];
    const float4 a1 = *(const float4*)&src[m * 128 + f0 + 4];
    const float4 bb = *(const float4*)&stb[m * 64 + n0];
    const float av[8] = {a0.x, a0.y, a0.z, a0.w, a1.x, a1.y, a1.z, a1.w};
    #pragma unroll
    for (int i = 0; i < 8; ++i) {
      acc[i][0] += av[i] * bb.x; acc[i][1] += av[i] * bb.y;
      acc[i][2] += av[i] * bb.z; acc[i][3] += av[i] * bb.w;
    }
  }
  #pragma unroll
  for (int i = 0; i < 8; ++i)
    *(float4*)&Mt[(f0 + i) * 64 + n0] = make_float4(acc[i][0], acc[i][1], acc[i][2], acc[i][3]);
}

// racc/uacc/cacc += Mt(k-range)^T @ {Wru_rows | Wc_rows}, merged (dense x-part). nch chunks of 8 k.
__device__ __forceinline__ void accum_PC(float* __restrict__ L,
    const float* __restrict__ w1g, const float* __restrict__ w2g, int nch,
    float racc[8][4], float uacc[8][4], float cacc[8][4], int tid)
{
  float* Ws = L + OFF_WS;
  const float* Mt = L + OFF_MT;
  const int tx = tid & 31, ty = tid >> 5;
  const int r0 = 8 * ty, c = 4 * tx;
  #pragma unroll
  for (int e = 0; e < 8; ++e) Ws[e * 384 + tid] = w1g[e * 256 + tid];
  #pragma unroll
  for (int e = 0; e < 4; ++e) { int idx = e * 256 + tid; Ws[(idx >> 7) * 384 + 256 + (idx & 127)] = w2g[idx]; }
  __syncthreads();
  for (int ch = 0; ch < nch; ++ch) {
    const int buf = (ch & 1) * 3072;
    float s1[8], s2[4];
    const bool more = (ch + 1 < nch);
    if (more) {
      const float* n1 = w1g + (ch + 1) * 8 * 256;
      const float* n2 = w2g + (ch + 1) * 8 * 128;
      #pragma unroll
      for (int e = 0; e < 8; ++e) s1[e] = n1[e * 256 + tid];
      #pragma unroll
      for (int e = 0; e < 4; ++e) s2[e] = n2[e * 256 + tid];
    }
    #pragma unroll
    for (int kk = 0; kk < 8; ++kk) {
      const float* mrow = Mt + (ch * 8 + kk) * 64;
      const float4 a0 = *(const float4*)&mrow[r0];
      const float4 a1 = *(const float4*)&mrow[r0 + 4];
      const float* wrow = Ws + buf + kk * 384;
      const float4 br = *(const float4*)&wrow[c];
      const float4 bu = *(const float4*)&wrow[128 + c];
      const float4 bc = *(const float4*)&wrow[256 + c];
      const float av[8] = {a0.x, a0.y, a0.z, a0.w, a1.x, a1.y, a1.z, a1.w};
      #pragma unroll
      for (int i = 0; i < 8; ++i) {
        racc[i][0] += av[i] * br.x; racc[i][1] += av[i] * br.y; racc[i][2] += av[i] * br.z; racc[i][3] += av[i] * br.w;
        uacc[i][0] += av[i] * bu.x; uacc[i][1] += av[i] * bu.y; uacc[i][2] += av[i] * bu.z; uacc[i][3] += av[i] * bu.w;
        cacc[i][0] += av[i] * bc.x; cacc[i][1] += av[i] * bc.y; cacc[i][2] += av[i] * bc.z; cacc[i][3] += av[i] * bc.w;
      }
    }
    if (more) {
      const int nbuf = ((ch + 1) & 1) * 3072;
      #pragma unroll
      for (int e = 0; e < 8; ++e) Ws[nbuf + e * 384 + tid] = s1[e];
      #pragma unroll
      for (int e = 0; e < 4; ++e) { int idx = e * 256 + tid; Ws[nbuf + (idx >> 7) * 384 + 256 + (idx & 127)] = s2[e]; }
    }
    __syncthreads();
  }
}

// racc/uacc += Mt^T @ Wru_rows (256-wide)
__device__ __forceinline__ void accum_P(float* __restrict__ L, const float* __restrict__ w1g, int nch,
    float racc[8][4], float uacc[8][4], int tid)
{
  float* Ws = L + OFF_WS;
  const float* Mt = L + OFF_MT;
  const int tx = tid & 31, ty = tid >> 5;
  const int r0 = 8 * ty, c = 4 * tx;
  #pragma unroll
  for (int e = 0; e < 8; ++e) Ws[e * 384 + tid] = w1g[e * 256 + tid];
  __syncthreads();
  for (int ch = 0; ch < nch; ++ch) {
    const int buf = (ch & 1) * 3072;
    float s1[8];
    const bool more = (ch + 1 < nch);
    if (more) {
      const float* n1 = w1g + (ch + 1) * 8 * 256;
      #pragma unroll
      for (int e = 0; e < 8; ++e) s1[e] = n1[e * 256 + tid];
    }
    #pragma unroll
    for (int kk = 0; kk < 8; ++kk) {
      const float* mrow = Mt + (ch * 8 + kk) * 64;
      const float4 a0 = *(const float4*)&mrow[r0];
      const float4 a1 = *(const float4*)&mrow[r0 + 4];
      const float* wrow = Ws + buf + kk * 384;
      const float4 br = *(const float4*)&wrow[c];
      const float4 bu = *(const float4*)&wrow[128 + c];
      const float av[8] = {a0.x, a0.y, a0.z, a0.w, a1.x, a1.y, a1.z, a1.w};
      #pragma unroll
      for (int i = 0; i < 8; ++i) {
        racc[i][0] += av[i] * br.x; racc[i][1] += av[i] * br.y; racc[i][2] += av[i] * br.z; racc[i][3] += av[i] * br.w;
        uacc[i][0] += av[i] * bu.x; uacc[i][1] += av[i] * bu.y; uacc[i][2] += av[i] * bu.z; uacc[i][3] += av[i] * bu.w;
      }
    }
    if (more) {
      const int nbuf = ((ch + 1) & 1) * 3072;
      #pragma unroll
      for (int e = 0; e < 8; ++e) Ws[nbuf + e * 384 + tid] = s1[e];
    }
    __syncthreads();
  }
}

// cacc += Mt^T @ Wc_rows (128-wide)
__device__ __forceinline__ void accum_C(float* __restrict__ L, const float* __restrict__ w2g, int nch,
    float cacc[8][4], int tid)
{
  float* Ws = L + OFF_WS;
  const float* Mt = L + OFF_MT;
  const int tx = tid & 31, ty = tid >> 5;
  const int r0 = 8 * ty, c = 4 * tx;
  #pragma unroll
  for (int e = 0; e < 4; ++e) { int idx = e * 256 + tid; Ws[(idx >> 7) * 384 + (idx & 127)] = w2g[idx]; }
  __syncthreads();
  for (int ch = 0; ch < nch; ++ch) {
    const int buf = (ch & 1) * 3072;
    float s2[4];
    const bool more = (ch + 1 < nch);
    if (more) {
      const float* n2 = w2g + (ch + 1) * 8 * 128;
      #pragma unroll
      for (int e = 0; e < 4; ++e) s2[e] = n2[e * 256 + tid];
    }
    #pragma unroll
    for (int kk = 0; kk < 8; ++kk) {
      const float* mrow = Mt + (ch * 8 + kk) * 64;
      const float4 a0 = *(const float4*)&mrow[r0];
      const float4 a1 = *(const float4*)&mrow[r0 + 4];
      const float* wrow = Ws + buf + kk * 384;
      const float4 bc = *(const float4*)&wrow[c];
      const float av[8] = {a0.x, a0.y, a0.z, a0.w, a1.x, a1.y, a1.z, a1.w};
      #pragma unroll
      for (int i = 0; i < 8; ++i) {
        cacc[i][0] += av[i] * bc.x; cacc[i][1] += av[i] * bc.y; cacc[i][2] += av[i] * bc.z; cacc[i][3] += av[i] * bc.w;
      }
    }
    if (more) {
      const int nbuf = ((ch + 1) & 1) * 3072;
      #pragma unroll
      for (int e = 0; e < 4; ++e) { int idx = e * 256 + tid; Ws[nbuf + (idx >> 7) * 384 + (idx & 127)] = s2[e]; }
    }
    __syncthreads();
  }
}

// ---- epilogue shared by both cell types ----------------------------------
__device__ __forceinline__ void cell_tail(float* __restrict__ L, float* __restrict__ h,
    const float* __restrict__ stb, const float* __restrict__ Wc_hrows, const float* __restrict__ brug,
    const float* __restrict__ bcg, float racc[8][4], float uacc[8][4], float cacc[8][4], int tid)
{
  const int tx = tid & 31, ty = tid >> 5;
  const int r0 = 8 * ty, c = 4 * tx;
  float u_[8][4], r_[8][4];
  float b1[4], b2[4], b3[4];
  #pragma unroll
  for (int j = 0; j < 4; ++j) { b1[j] = brug[c + j]; b2[j] = brug[128 + c + j]; b3[j] = bcg[c + j]; }
  #pragma unroll
  for (int i = 0; i < 8; ++i)
    #pragma unroll
    for (int j = 0; j < 4; ++j) {
      r_[i][j] = sigm(racc[i][j] + b1[j]);
      u_[i][j] = sigm(uacc[i][j] + b2[j]);
    }
  float* Rh = L + OFF_RH;
  #pragma unroll
  for (int i = 0; i < 8; ++i) {
    const float4 h4 = *(const float4*)&h[(r0 + i) * 128 + c];
    *(float4*)&Rh[(r0 + i) * 128 + c] =
        make_float4(r_[i][0] * h4.x, r_[i][1] * h4.y, r_[i][2] * h4.z, r_[i][3] * h4.w);
  }
  __syncthreads();
  mixt(L + OFF_MT, Rh, stb, tid);
  __syncthreads();
  accum_C(L, Wc_hrows, 16, cacc, tid);
  #pragma unroll
  for (int i = 0; i < 8; ++i) {
    const float4 h4 = *(const float4*)&h[(r0 + i) * 128 + c];
    float cv[4];
    #pragma unroll
    for (int j = 0; j < 4; ++j) cv[j] = tanhf(cacc[i][j] + b3[j]);
    *(float4*)&h[(r0 + i) * 128 + c] = make_float4(
        u_[i][0] * h4.x + (1.f - u_[i][0]) * cv[0],
        u_[i][1] * h4.y + (1.f - u_[i][1]) * cv[1],
        u_[i][2] * h4.z + (1.f - u_[i][2]) * cv[2],
        u_[i][3] * h4.w + (1.f - u_[i][3]) * cv[3]);
  }
}

// Din=1 cell. xg: global [64] or ignored when !hasx (treated as zeros).
__device__ __forceinline__ void cell_sparse(float* __restrict__ L, int b, int tid,
    const float* __restrict__ xg, float* __restrict__ h,
    const float* __restrict__ Wru, const float* __restrict__ bru,
    const float* __restrict__ Wc, const float* __restrict__ bc,
    const float* __restrict__ stb, const float* __restrict__ Sg, bool hasx)
{
  __syncthreads();
  if (hasx) {
    if (tid < 64) (L + OFF_XS)[tid] = xg[tid];
    (L + OFF_W0RU)[tid] = Wru[tid];              // row 0 of Wru [256]
    if (tid < 128) (L + OFF_W0C)[tid] = Wc[tid]; // row 0 of Wc [128]
    __syncthreads();
    {
      const int r = tid & 63, q = tid >> 6;
      const float* srow = Sg + ((size_t)b * 64 + r) * 64 + q * 16;
      const float* xsv = L + OFF_XS + q * 16;
      float s = 0.f;
      #pragma unroll
      for (int m = 0; m < 16; m += 4) {
        const float4 s4 = *(const float4*)&srow[m];
        s += s4.x * xsv[m] + s4.y * xsv[m + 1] + s4.z * xsv[m + 2] + s4.w * xsv[m + 3];
      }
      (L + OFF_MP)[q * 64 + r] = s;
    }
    __syncthreads();
    if (tid < 64) {
      const float* mp = L + OFF_MP;
      (L + OFF_MXV)[tid] = mp[tid] + mp[64 + tid] + mp[128 + tid] + mp[192 + tid];
    }
  }
  mixt(L + OFF_MT, h, stb, tid);   // Mt = (S@h)^T
  __syncthreads();
  float racc[8][4], uacc[8][4], cacc[8][4];
  #pragma unroll
  for (int i = 0; i < 8; ++i)
    #pragma unroll
    for (int j = 0; j < 4; ++j) { racc[i][j] = 0.f; uacc[i][j] = 0.f; cacc[i][j] = 0.f; }
  if (hasx) {
    const int tx = tid & 31, ty = tid >> 5;
    const int r0 = 8 * ty, c = 4 * tx;
    const float4 m0 = *(const float4*)&(L + OFF_MXV)[r0];
    const float4 m1 = *(const float4*)&(L + OFF_MXV)[r0 + 4];
    const float mv[8] = {m0.x, m0.y, m0.z, m0.w, m1.x, m1.y, m1.z, m1.w};
    const float4 w0r = *(const float4*)&(L + OFF_W0RU)[c];
    const float4 w0u = *(const float4*)&(L + OFF_W0RU)[128 + c];
    const float4 w0c = *(const float4*)&(L + OFF_W0C)[c];
    #pragma unroll
    for (int i = 0; i < 8; ++i) {
      racc[i][0] += mv[i] * w0r.x; racc[i][1] += mv[i] * w0r.y; racc[i][2] += mv[i] * w0r.z; racc[i][3] += mv[i] * w0r.w;
      uacc[i][0] += mv[i] * w0u.x; uacc[i][1] += mv[i] * w0u.y; uacc[i][2] += mv[i] * w0u.z; uacc[i][3] += mv[i] * w0u.w;
      cacc[i][0] += mv[i] * w0c.x; cacc[i][1] += mv[i] * w0c.y; cacc[i][2] += mv[i] * w0c.z; cacc[i][3] += mv[i] * w0c.w;
    }
  }
  accum_P(L, Wru + 256, 16, racc, uacc, tid);   // h-rows (rows 1..128)
  cell_tail(L, h, stb, Wc + 128, bru, bc, racc, uacc, cacc, tid);
}

// Din=128 cell. x: LDS [64][128] (the other layer's state).
__device__ __forceinline__ void cell_dense(float* __restrict__ L, int tid,
    const float* __restrict__ x, float* __restrict__ h,
    const float* __restrict__ Wru, const float* __restrict__ bru,
    const float* __restrict__ Wc, const float* __restrict__ bc,
    const float* __restrict__ stb)
{
  __syncthreads();
  mixt(L + OFF_MT, x, stb, tid);   // Mt = (S@x)^T
  __syncthreads();
  float racc[8][4], uacc[8][4], cacc[8][4];
  #pragma unroll
  for (int i = 0; i < 8; ++i)
    #pragma unroll
    for (int j = 0; j < 4; ++j) { racc[i][j] = 0.f; uacc[i][j] = 0.f; cacc[i][j] = 0.f; }
  accum_PC(L, Wru, Wc, 16, racc, uacc, cacc, tid);      // x-rows (0..127), P and C merged
  mixt(L + OFF_MT, h, stb, tid);                         // Mt = (S@h)^T
  __syncthreads();
  accum_P(L, Wru + 128 * 256, 16, racc, uacc, tid);      // h-rows
  cell_tail(L, h, stb, Wc + 128 * 128, bru, bc, racc, uacc, cacc, tid);
}

__device__ __forceinline__ void proj(float* __restrict__ L, const float* __restrict__ h1,
    const float* __restrict__ bpg, float* __restrict__ outg, int tid)
{
  __syncthreads();
  const int n = tid & 63, q = tid >> 6;
  const float* hp = h1 + n * 128 + q * 32;
  const float* wp = L + OFF_WP + q * 32;
  float s = 0.f;
  #pragma unroll
  for (int m = 0; m < 32; m += 4) {
    const float4 h4 = *(const float4*)&hp[m];
    const float4 w4 = *(const float4*)&wp[m];
    s += h4.x * w4.x + h4.y * w4.y + h4.z * w4.z + h4.w * w4.w;
  }
  (L + OFF_MP)[q * 64 + n] = s;
  __syncthreads();
  if (tid < 64) {
    const float* mp = L + OFF_MP;
    outg[tid] = mp[tid] + mp[64 + tid] + mp[128 + tid] + mp[192 + tid] + bpg[0];
  }
}

__global__ __launch_bounds__(256, 1) void gcgru_persist(KParams p)
{
  extern __shared__ float L[];
  const int b = blockIdx.x, tid = threadIdx.x;
  float* h0 = L + OFF_H0;
  float* h1 = L + OFF_H1;
  for (int i = tid; i < 16384; i += 256) L[i] = 0.f;   // zero h0,h1
  if (tid < 128) (L + OFF_WP)[tid] = p.Wp[tid];
  // transpose this batch's S into ws: stb[m*64+r] = S[b][r][m]
  const float* Sb = p.S + (size_t)b * 4096;
  float* stb = p.stg + (size_t)b * 4096;
  for (int idx = tid; idx < 4096; idx += 256) {
    const int m = idx >> 6, r = idx & 63;
    stb[idx] = Sb[r * 64 + m];
  }
  __syncthreads();

  // ---- encoder: 2 stacked GCGRU layers, step-wise ----
  for (int t = 0; t < 32; ++t) {
    cell_sparse(L, b, tid, p.inp + ((size_t)t * 64 + b) * 64, h0,
                p.w[0], p.w[1], p.w[2], p.w[3], stb, p.S, true);
    cell_dense(L, tid, h0, h1, p.w[4], p.w[5], p.w[6], p.w[7], stb);
  }
  // ---- decoder: feedback through out ----
  for (int t = 0; t < 32; ++t) {
    const float* xg = (t > 0) ? (p.out + ((size_t)(t - 1) * 4096) + (size_t)b * 64) : p.out;
    cell_sparse(L, b, tid, xg, h0, p.w[8], p.w[9], p.w[10], p.w[11], stb, p.S, t > 0);
    cell_dense(L, tid, h0, h1, p.w[12], p.w[13], p.w[14], p.w[15], stb);
    proj(L, h1, p.bp, p.out + (size_t)t * 4096 + (size_t)b * 64, tid);
  }
}

extern "C" void kernel_launch(void* const* d_in, const int* in_sizes, int n_in,
                              void* d_out, int out_size, void* d_ws, size_t ws_size,
                              hipStream_t stream)
{
  KParams p;
  p.inp = (const float*)d_in[0];
  p.S   = (const float*)d_in[2];
  for (int i = 0; i < 16; ++i) p.w[i] = (const float*)d_in[3 + i];
  p.Wp = (const float*)d_in[19];
  p.bp = (const float*)d_in[20];
  p.out = (float*)d_out;
  p.stg = (float*)d_ws;   // 1 MB used

  (void)hipFuncSetAttribute((const void*)gcgru_persist,
                            hipFuncAttributeMaxDynamicSharedMemorySize, LDS_BYTES);
  gcgru_persist<<<dim3(NB), dim3(256), LDS_BYTES, stream>>>(p);
}

// Round 3
// 8265.164 us; speedup vs baseline: 1.0040x; 1.0040x over previous
//
#include <hip/hip_runtime.h>

// Problem constants: T=32 enc + 32 dec, B=64, N=64, H=128, Din=Dout=1
// One persistent block per batch (64 blocks, 512 threads = 8 waves = 2/SIMD).
// States + scratch in LDS; weights read directly from global (L1/L2-resident).

#define LDS_FLOATS 33344
#define LDS_BYTES  (LDS_FLOATS * 4)   // 133376 B <= 160 KiB

#define H0p (L + 0)       // [64][128] layer-0 state
#define H1p (L + 8192)    // [64][128] layer-1 state
#define B1p (L + 16384)   // [128][64] scratch (Mt layout)
#define B2p (L + 24576)   // [128][64] Mt  OR  [64][128] rh (generic 32KB scratch)
#define XSp (L + 32768)   // [64] sparse x
#define MPp (L + 32832)   // [8][64] partials

struct KParams {
  const float* inp;   // [32,64,64]
  const float* S;     // [64,64,64]
  const float* w[16]; // e0{Wru,bru,Wc,bc} e1{..} d0{..} db{..}
  const float* Wp;    // [128]
  const float* bp;    // [1]
  float* out;         // [32,64,64]
  float* stg;         // ws: S^T per batch: stb[m*64+r] = S[b][r][m]
};

__device__ __forceinline__ float sigm(float v) { return 1.f / (1.f + __expf(-v)); }

// dst[f][n] = (S @ src)^T : dst[f*64+n] = sum_m src[m*128+f] * stb[m*64+n]
// src: LDS [64][128]; stb: global (L1/L2). Tile: 4 feats x 4 nodes.
__device__ __forceinline__ void mixt(float* __restrict__ dst, const float* __restrict__ src,
                                     const float* __restrict__ stb, int tid)
{
  const int n0 = (tid & 15) * 4, f0 = (tid >> 4) * 4;
  float acc[4][4];
  #pragma unroll
  for (int i = 0; i < 4; ++i)
    #pragma unroll
    for (int j = 0; j < 4; ++j) acc[i][j] = 0.f;
  #pragma unroll 4
  for (int m = 0; m < 64; ++m) {
    const float4 a4 = *(const float4*)&src[m * 128 + f0];
    const float4 b4 = *(const float4*)&stb[m * 64 + n0];
    const float av[4] = {a4.x, a4.y, a4.z, a4.w};
    const float bv[4] = {b4.x, b4.y, b4.z, b4.w};
    #pragma unroll
    for (int i = 0; i < 4; ++i)
      #pragma unroll
      for (int j = 0; j < 4; ++j) acc[i][j] += av[i] * bv[j];
  }
  #pragma unroll
  for (int i = 0; i < 4; ++i)
    *(float4*)&dst[(f0 + i) * 64 + n0] = make_float4(acc[i][0], acc[i][1], acc[i][2], acc[i][3]);
}

// racc/uacc += Mt^T @ Wru-rows.  Mt: LDS [128][64]; w1: global, stride 256 (r cols 0..127, u cols 128..255)
__device__ __forceinline__ void accum_ru(const float* __restrict__ Mt, const float* __restrict__ w1,
    float racc[4][4], float uacc[4][4], int r0, int c)
{
  #pragma unroll 4
  for (int kk = 0; kk < 128; ++kk) {
    const float4 a4 = *(const float4*)&Mt[kk * 64 + r0];
    const float4 wr = *(const float4*)&w1[kk * 256 + c];
    const float4 wu = *(const float4*)&w1[kk * 256 + 128 + c];
    const float av[4] = {a4.x, a4.y, a4.z, a4.w};
    const float wrv[4] = {wr.x, wr.y, wr.z, wr.w};
    const float wuv[4] = {wu.x, wu.y, wu.z, wu.w};
    #pragma unroll
    for (int i = 0; i < 4; ++i)
      #pragma unroll
      for (int j = 0; j < 4; ++j) {
        racc[i][j] += av[i] * wrv[j];
        uacc[i][j] += av[i] * wuv[j];
      }
  }
}

// racc/uacc/cacc += Mt^T @ {Wru-rows, Wc-rows} merged (dense x-part).
__device__ __forceinline__ void accum_ruc(const float* __restrict__ Mt, const float* __restrict__ w1,
    const float* __restrict__ w2, float racc[4][4], float uacc[4][4], float cacc[4][4], int r0, int c)
{
  #pragma unroll 4
  for (int kk = 0; kk < 128; ++kk) {
    const float4 a4 = *(const float4*)&Mt[kk * 64 + r0];
    const float4 wr = *(const float4*)&w1[kk * 256 + c];
    const float4 wu = *(const float4*)&w1[kk * 256 + 128 + c];
    const float4 wc = *(const float4*)&w2[kk * 128 + c];
    const float av[4] = {a4.x, a4.y, a4.z, a4.w};
    const float wrv[4] = {wr.x, wr.y, wr.z, wr.w};
    const float wuv[4] = {wu.x, wu.y, wu.z, wu.w};
    const float wcv[4] = {wc.x, wc.y, wc.z, wc.w};
    #pragma unroll
    for (int i = 0; i < 4; ++i)
      #pragma unroll
      for (int j = 0; j < 4; ++j) {
        racc[i][j] += av[i] * wrv[j];
        uacc[i][j] += av[i] * wuv[j];
        cacc[i][j] += av[i] * wcv[j];
      }
  }
}

// cacc += Mt^T @ Wc-rows. w2: global, stride 128.
__device__ __forceinline__ void accum_c(const float* __restrict__ Mt, const float* __restrict__ w2,
    float cacc[4][4], int r0, int c)
{
  #pragma unroll 4
  for (int kk = 0; kk < 128; ++kk) {
    const float4 a4 = *(const float4*)&Mt[kk * 64 + r0];
    const float4 wc = *(const float4*)&w2[kk * 128 + c];
    const float av[4] = {a4.x, a4.y, a4.z, a4.w};
    const float wcv[4] = {wc.x, wc.y, wc.z, wc.w};
    #pragma unroll
    for (int i = 0; i < 4; ++i)
      #pragma unroll
      for (int j = 0; j < 4; ++j) cacc[i][j] += av[i] * wcv[j];
  }
}

// shared epilogue: r,u -> rh -> mix -> c-accum -> combine into h
__device__ __forceinline__ void cell_tail(float* __restrict__ L, float* __restrict__ h,
    const float* __restrict__ stb, const float* __restrict__ wc_h,
    const float* __restrict__ bru, const float* __restrict__ bc,
    float racc[4][4], float uacc[4][4], float cacc[4][4], int tid)
{
  const int c = (tid & 31) * 4, r0 = (tid >> 5) * 4;
  const float4 bq1 = *(const float4*)&bru[c];
  const float4 bq2 = *(const float4*)&bru[128 + c];
  const float b1v[4] = {bq1.x, bq1.y, bq1.z, bq1.w};
  const float b2v[4] = {bq2.x, bq2.y, bq2.z, bq2.w};
  float r_[4][4], u_[4][4];
  #pragma unroll
  for (int i = 0; i < 4; ++i)
    #pragma unroll
    for (int j = 0; j < 4; ++j) {
      r_[i][j] = sigm(racc[i][j] + b1v[j]);
      u_[i][j] = sigm(uacc[i][j] + b2v[j]);
    }
  __syncthreads();   // all readers of B2 (accum_ruc / sparse mix) are done
  #pragma unroll
  for (int i = 0; i < 4; ++i) {
    const float4 h4 = *(const float4*)&h[(r0 + i) * 128 + c];
    *(float4*)&B2p[(r0 + i) * 128 + c] =
        make_float4(r_[i][0] * h4.x, r_[i][1] * h4.y, r_[i][2] * h4.z, r_[i][3] * h4.w);
  }
  __syncthreads();   // rh complete
  mixt(B1p, B2p, stb, tid);   // B1 readers finished before previous barrier
  __syncthreads();   // S@rh complete
  accum_c(B1p, wc_h, cacc, r0, c);
  const float4 bq3 = *(const float4*)&bc[c];
  const float b3v[4] = {bq3.x, bq3.y, bq3.z, bq3.w};
  #pragma unroll
  for (int i = 0; i < 4; ++i) {
    const float4 h4 = *(const float4*)&h[(r0 + i) * 128 + c];
    const float hv[4] = {h4.x, h4.y, h4.z, h4.w};
    float nv[4];
    #pragma unroll
    for (int j = 0; j < 4; ++j) {
      float cv = tanhf(cacc[i][j] + b3v[j]);
      nv[j] = u_[i][j] * hv[j] + (1.f - u_[i][j]) * cv;
    }
    *(float4*)&h[(r0 + i) * 128 + c] = make_float4(nv[0], nv[1], nv[2], nv[3]);
  }
  __syncthreads();   // h ready for next cell
}

// Din=128 cell: x is an LDS state [64][128]
__device__ __forceinline__ void cell_dense(float* __restrict__ L, int tid,
    const float* __restrict__ x, float* __restrict__ h,
    const float* __restrict__ Wru, const float* __restrict__ bru,
    const float* __restrict__ Wc, const float* __restrict__ bc,
    const float* __restrict__ stb)
{
  mixt(B2p, x, stb, tid);   // (S@x)^T
  mixt(B1p, h, stb, tid);   // (S@h)^T
  __syncthreads();
  const int c = (tid & 31) * 4, r0 = (tid >> 5) * 4;
  float racc[4][4] = {{0.f}}, uacc[4][4] = {{0.f}}, cacc[4][4] = {{0.f}};
  accum_ruc(B2p, Wru, Wc, racc, uacc, cacc, r0, c);        // x-rows 0..127
  accum_ru(B1p, Wru + 128 * 256, racc, uacc, r0, c);       // h-rows 128..255
  cell_tail(L, h, stb, Wc + 128 * 128, bru, bc, racc, uacc, cacc, tid);
}

// Din=1 cell: x (if any) is XS[64]; rank-1 x-term via S@x.
__device__ __forceinline__ void cell_sparse(float* __restrict__ L, int tid,
    const float* __restrict__ xg, bool hasx, float* __restrict__ h,
    const float* __restrict__ Wru, const float* __restrict__ bru,
    const float* __restrict__ Wc, const float* __restrict__ bc,
    const float* __restrict__ stb, const float* __restrict__ Sb)
{
  if (xg && tid < 64) XSp[tid] = xg[tid];   // decoder keeps XS from proj
  mixt(B1p, h, stb, tid);                   // (S@h)^T
  __syncthreads();                          // B1 + XS ready
  const int c = (tid & 31) * 4, r0 = (tid >> 5) * 4;
  if (hasx) {                               // MP[q][r] = partial dot(S[r, 8q..8q+8), x)
    const int q = tid & 7, rr = tid >> 3;
    const float* srow = Sb + rr * 64 + q * 8;
    const float* xv = XSp + q * 8;
    const float4 s0 = *(const float4*)&srow[0];
    const float4 s1 = *(const float4*)&srow[4];
    MPp[q * 64 + rr] = s0.x * xv[0] + s0.y * xv[1] + s0.z * xv[2] + s0.w * xv[3]
                     + s1.x * xv[4] + s1.y * xv[5] + s1.z * xv[6] + s1.w * xv[7];
  }
  float racc[4][4] = {{0.f}}, uacc[4][4] = {{0.f}}, cacc[4][4] = {{0.f}};
  accum_ru(B1p, Wru + 256, racc, uacc, r0, c);   // h-rows (rows 1..128)
  __syncthreads();                               // MP ready
  if (hasx) {
    float4 mv = make_float4(0.f, 0.f, 0.f, 0.f);
    #pragma unroll
    for (int q = 0; q < 8; ++q) {
      const float4 m4 = *(const float4*)&MPp[q * 64 + r0];
      mv.x += m4.x; mv.y += m4.y; mv.z += m4.z; mv.w += m4.w;
    }
    const float mva[4] = {mv.x, mv.y, mv.z, mv.w};
    const float4 w0r = *(const float4*)&Wru[c];
    const float4 w0u = *(const float4*)&Wru[128 + c];
    const float4 w0c = *(const float4*)&Wc[c];
    const float w0rv[4] = {w0r.x, w0r.y, w0r.z, w0r.w};
    const float w0uv[4] = {w0u.x, w0u.y, w0u.z, w0u.w};
    const float w0cv[4] = {w0c.x, w0c.y, w0c.z, w0c.w};
    #pragma unroll
    for (int i = 0; i < 4; ++i)
      #pragma unroll
      for (int j = 0; j < 4; ++j) {
        racc[i][j] += mva[i] * w0rv[j];
        uacc[i][j] += mva[i] * w0uv[j];
        cacc[i][j] += mva[i] * w0cv[j];
      }
  }
  cell_tail(L, h, stb, Wc + 128, bru, bc, racc, uacc, cacc, tid);
}

__device__ __forceinline__ void proj(float* __restrict__ L, const float* __restrict__ Wp,
    const float* __restrict__ bp, float* __restrict__ outg, int tid)
{
  const int n = tid & 63, q = tid >> 6;
  const float* hp = H1p + n * 128 + q * 16;
  const float* wp = Wp + q * 16;
  float s = 0.f;
  #pragma unroll
  for (int m = 0; m < 16; m += 4) {
    const float4 h4 = *(const float4*)&hp[m];
    const float4 w4 = *(const float4*)&wp[m];
    s += h4.x * w4.x + h4.y * w4.y + h4.z * w4.z + h4.w * w4.w;
  }
  MPp[q * 64 + n] = s;
  __syncthreads();
  if (tid < 64) {
    float v = bp[0];
    #pragma unroll
    for (int q2 = 0; q2 < 8; ++q2) v += MPp[q2 * 64 + tid];
    outg[tid] = v;
    XSp[tid] = v;    // decoder feedback stays in LDS
  }
  __syncthreads();
}

__global__ __launch_bounds__(512, 2) void gcgru_persist(KParams p)
{
  extern __shared__ float L[];
  const int b = blockIdx.x, tid = threadIdx.x;
  for (int i = tid; i < 16384; i += 512) L[i] = 0.f;   // zero h0,h1
  const float* Sb = p.S + (size_t)b * 4096;
  float* stb = p.stg + (size_t)b * 4096;
  for (int idx = tid; idx < 4096; idx += 512)
    stb[idx] = Sb[(idx & 63) * 64 + (idx >> 6)];       // stb[m][r] = S[r][m]
  __syncthreads();

  // encoder: two stacked GCGRU layers, step-wise
  for (int t = 0; t < 32; ++t) {
    cell_sparse(L, tid, p.inp + ((size_t)t * 64 + b) * 64, true, H0p,
                p.w[0], p.w[1], p.w[2], p.w[3], stb, Sb);
    cell_dense(L, tid, H0p, H1p, p.w[4], p.w[5], p.w[6], p.w[7], stb);
  }
  // decoder: proj feedback through XS (LDS) + out (global)
  for (int t = 0; t < 32; ++t) {
    cell_sparse(L, tid, nullptr, t > 0, H0p,
                p.w[8], p.w[9], p.w[10], p.w[11], stb, Sb);
    cell_dense(L, tid, H0p, H1p, p.w[12], p.w[13], p.w[14], p.w[15], stb);
    proj(L, p.Wp, p.bp, p.out + (size_t)t * 4096 + (size_t)b * 64, tid);
  }
}

extern "C" void kernel_launch(void* const* d_in, const int* in_sizes, int n_in,
                              void* d_out, int out_size, void* d_ws, size_t ws_size,
                              hipStream_t stream)
{
  KParams p;
  p.inp = (const float*)d_in[0];
  p.S   = (const float*)d_in[2];
  for (int i = 0; i < 16; ++i) p.w[i] = (const float*)d_in[3 + i];
  p.Wp = (const float*)d_in[19];
  p.bp = (const float*)d_in[20];
  p.out = (float*)d_out;
  p.stg = (float*)d_ws;   // 1 MB used for S^T

  (void)hipFuncSetAttribute((const void*)gcgru_persist,
                            hipFuncAttributeMaxDynamicSharedMemorySize, LDS_BYTES);
  gcgru_persist<<<dim3(64), dim3(512), LDS_BYTES, stream>>>(p);
}